// Round 1
// baseline (131.855 us; speedup 1.0000x reference)
//
#include <hip/hip_runtime.h>

#define K 5
#define KK 25
#define HW 256
#define C 32
#define PAD 2
#define TW 32
#define TH 8
#define LW (TW + 2*PAD)   // 36
#define LH (TH + 2*PAD)   // 12
#define NTHREADS (TW*TH)  // 256

__global__ __launch_bounds__(NTHREADS) void ddown_kernel(
    const float* __restrict__ x,
    const float* __restrict__ kern,
    float* __restrict__ out)
{
    __shared__ float xt[LH * LW];

    const int tid = threadIdx.x;
    const int tx  = tid & (TW - 1);
    const int ty  = tid >> 5;          // TW == 32
    const int b   = blockIdx.z;
    const int h0  = blockIdx.y * TH;
    const int w0  = blockIdx.x * TW;
    const int h   = h0 + ty;
    const int w   = w0 + tx;

    // ---- softmax over 25 taps for this pixel (weights live in VGPRs) ----
    const float* kb = kern + (size_t)b * KK * (HW * HW) + h * HW + w;
    float wt[KK];
    float m = -1e30f;
#pragma unroll
    for (int j = 0; j < KK; ++j) {
        wt[j] = kb[(size_t)j * (HW * HW)];
        m = fmaxf(m, wt[j]);
    }
    float s = 0.f;
#pragma unroll
    for (int j = 0; j < KK; ++j) {
        wt[j] = __expf(wt[j] - m);
        s += wt[j];
    }
    const float inv = 1.0f / s;
#pragma unroll
    for (int j = 0; j < KK; ++j) wt[j] *= inv;

    const size_t xbase = (size_t)b * C * (HW * HW);
    float* ob = out + xbase + h * HW + w;

    // ---- per-channel: stage x tile (with edge clamp) into LDS, weighted sum ----
    for (int c = 0; c < C; ++c) {
        const float* xc = x + xbase + (size_t)c * (HW * HW);
        __syncthreads();   // protect previous iteration's reads before overwrite
#pragma unroll
        for (int idx = tid; idx < LH * LW; idx += NTHREADS) {
            int i = idx / LW;
            int j = idx - i * LW;
            int hh = h0 + i - PAD; hh = min(max(hh, 0), HW - 1);
            int ww = w0 + j - PAD; ww = min(max(ww, 0), HW - 1);
            xt[idx] = xc[hh * HW + ww];
        }
        __syncthreads();

        float acc = 0.f;
#pragma unroll
        for (int di = 0; di < K; ++di) {
#pragma unroll
            for (int dj = 0; dj < K; ++dj) {
                acc += wt[di * K + dj] * xt[(ty + di) * LW + (tx + dj)];
            }
        }
        ob[(size_t)c * (HW * HW)] = acc;
    }
}

extern "C" void kernel_launch(void* const* d_in, const int* in_sizes, int n_in,
                              void* d_out, int out_size, void* d_ws, size_t ws_size,
                              hipStream_t stream) {
    const float* x    = (const float*)d_in[0];
    const float* kern = (const float*)d_in[1];
    float* out        = (float*)d_out;

    dim3 grid(HW / TW, HW / TH, 4);   // (8, 32, 4) = 1024 blocks
    ddown_kernel<<<grid, NTHREADS, 0, stream>>>(x, kern, out);
}

// Round 2
// 110.521 us; speedup vs baseline: 1.1930x; 1.1930x over previous
//
#include <hip/hip_runtime.h>

#define HW    256
#define HW2   (HW*HW)
#define KTAPS 25
#define TW    32          // tile width  (outputs)
#define TH    8           // tile height (outputs)
#define LW    36          // LDS row length (TW + 4); 36*4=144 B, 16B-aligned rows
#define LH    12          // TH + 4
#define NEL   (LW*LH)     // 432
#define NSTG  7           // ceil(432/64)
#define CPB   8           // channels per block (channel-split = 4)
#define C     32

// Issue global loads for one channel tile into registers (clamped edge-replicate).
__device__ __forceinline__ void stage_issue(float r[NSTG], const float* __restrict__ xc,
                                            int lane, int h0, int w0) {
#pragma unroll
    for (int k = 0; k < NSTG; ++k) {
        int idx = lane + k * 64;
        if (idx < NEL) {
            int i  = idx / LW;
            int j  = idx - i * LW;
            int hh = min(max(h0 + i - 2, 0), HW - 1);
            int ww = min(max(w0 + j - 2, 0), HW - 1);
            r[k] = xc[hh * HW + ww];
        }
    }
}

__global__ __launch_bounds__(64, 3) void ddown_kernel(
    const float* __restrict__ x,
    const float* __restrict__ kern,
    float* __restrict__ out)
{
    __shared__ __align__(16) float xt[NEL];

    const int lane = threadIdx.x;      // one wave per block: no __syncthreads anywhere
    const int txq  = lane & 7;         // 8 thread-columns of 4 outputs
    const int ty   = lane >> 3;        // 8 rows
    const int w0   = blockIdx.x * TW;
    const int h0   = blockIdx.y * TH;
    const int b    = blockIdx.z >> 2;
    const int c0   = (blockIdx.z & 3) * CPB;

    const int h = h0 + ty;
    const int w = w0 + txq * 4;

    const float* xb = x + (size_t)(b * C + c0) * HW2;

    // Prefetch channel c0's tile while we do the softmax.
    float r[NSTG];
    stage_issue(r, xb, lane, h0, w0);

    // ---- softmax weights for this thread's 4 pixels (unnormalized; fold 1/S later) ----
    const float* kb = kern + (size_t)b * KTAPS * HW2 + h * HW + w;
    float4 wt[KTAPS];
    float sx = 0.f, sy = 0.f, sz = 0.f, sw = 0.f;
#pragma unroll
    for (int j = 0; j < KTAPS; ++j) {
        float4 v = *(const float4*)(kb + (size_t)j * HW2);
        v.x = __expf(v.x); v.y = __expf(v.y); v.z = __expf(v.z); v.w = __expf(v.w);
        sx += v.x; sy += v.y; sz += v.z; sw += v.w;
        wt[j] = v;
    }
    const float ix = 1.f / sx, iy = 1.f / sy, iz = 1.f / sz, iw = 1.f / sw;

    float* ob = out + (size_t)(b * C + c0) * HW2 + h * HW + w;

    for (int cc = 0; cc < CPB; ++cc) {
        // commit prefetched tile to LDS (same-wave DS ordering makes this safe barrier-free)
#pragma unroll
        for (int k = 0; k < NSTG; ++k) {
            int idx = lane + k * 64;
            if (idx < NEL) xt[idx] = r[k];
        }
        // prefetch next channel during compute
        if (cc + 1 < CPB) stage_issue(r, xb + (size_t)(cc + 1) * HW2, lane, h0, w0);

        float ax = 0.f, ay = 0.f, az = 0.f, aw = 0.f;
#pragma unroll
        for (int di = 0; di < 5; ++di) {
            const float* row = &xt[(ty + di) * LW + txq * 4];
            float4 pa = *(const float4*)(row);      // ds_read_b128
            float4 pb = *(const float4*)(row + 4);  // ds_read_b128
            float w8[8] = {pa.x, pa.y, pa.z, pa.w, pb.x, pb.y, pb.z, pb.w};
#pragma unroll
            for (int dj = 0; dj < 5; ++dj) {
                float4 wv = wt[di * 5 + dj];
                ax += wv.x * w8[dj + 0];
                ay += wv.y * w8[dj + 1];
                az += wv.z * w8[dj + 2];
                aw += wv.w * w8[dj + 3];
            }
        }
        float4 res = { ax * ix, ay * iy, az * iz, aw * iw };
        *(float4*)(ob + (size_t)cc * HW2) = res;
    }
}

extern "C" void kernel_launch(void* const* d_in, const int* in_sizes, int n_in,
                              void* d_out, int out_size, void* d_ws, size_t ws_size,
                              hipStream_t stream) {
    const float* x    = (const float*)d_in[0];
    const float* kern = (const float*)d_in[1];
    float* out        = (float*)d_out;

    dim3 grid(HW / TW, HW / TH, 4 * 4);   // (8, 32, 16) = 4096 single-wave blocks
    ddown_kernel<<<grid, 64, 0, stream>>>(x, kern, out);
}